// Round 1
// baseline (674.390 us; speedup 1.0000x reference)
//
#include <hip/hip_runtime.h>
#include <math.h>

#define CN 4096
#define KDIM 256
#define ND 256   // H * D
#define NH 4
#define DD 64
#define NEG 0.2f

// ---------------- Kernel A: h = x @ W  (4096x256 = 4096x256 @ 256x256, fp32)
// 64x64 tile per block, 256 threads, 4x4 per thread, K-chunks of 16.
__global__ __launch_bounds__(256) void k_gemm_h(const float* __restrict__ x,
                                                const float* __restrict__ W,
                                                float* __restrict__ h) {
  __shared__ float As[16][68];  // [k][i]  (transposed store, padded)
  __shared__ float Bs[16][68];  // [k][c]  (padded)
  const int t = threadIdx.x;
  const int tx = t & 15, ty = t >> 4;
  const int i0 = blockIdx.y * 64, c0 = blockIdx.x * 64;
  float acc[4][4] = {};
  for (int k0 = 0; k0 < KDIM; k0 += 16) {
    __syncthreads();
    {
      const int kc = t & 15;
      const int ib = t >> 4;
#pragma unroll
      for (int p = 0; p < 4; ++p) {
        const int i = p * 16 + ib;
        As[kc][i] = x[(size_t)(i0 + i) * KDIM + k0 + kc];
      }
      const int c = t & 63;
      const int kb = t >> 6;
#pragma unroll
      for (int p = 0; p < 4; ++p) {
        const int k = p * 4 + kb;
        Bs[k][c] = W[(size_t)(k0 + k) * ND + c0 + c];
      }
    }
    __syncthreads();
#pragma unroll
    for (int kk = 0; kk < 16; ++kk) {
      const float4 a4 = *(const float4*)&As[kk][ty * 4];
      const float4 b4 = *(const float4*)&Bs[kk][tx * 4];
      const float a[4] = {a4.x, a4.y, a4.z, a4.w};
      const float b[4] = {b4.x, b4.y, b4.z, b4.w};
#pragma unroll
      for (int ii = 0; ii < 4; ++ii)
#pragma unroll
        for (int cc = 0; cc < 4; ++cc) acc[ii][cc] += a[ii] * b[cc];
    }
  }
#pragma unroll
  for (int ii = 0; ii < 4; ++ii) {
    float4 v = make_float4(acc[ii][0], acc[ii][1], acc[ii][2], acc[ii][3]);
    *(float4*)&h[(size_t)(i0 + ty * 4 + ii) * ND + c0 + tx * 4] = v;
  }
}

// ---------------- Kernel B: alpha_src[h][c], alpha_dst[h][c]
// One wave per node c; lane = d; butterfly reduce over 64 lanes.
__global__ __launch_bounds__(256) void k_alpha(const float* __restrict__ h,
                                               const float* __restrict__ a_src,
                                               const float* __restrict__ a_dst,
                                               float* __restrict__ asrc,
                                               float* __restrict__ adst) {
  const int wave = threadIdx.x >> 6;
  const int lane = threadIdx.x & 63;
  const int c = blockIdx.x * 4 + wave;
#pragma unroll
  for (int hd = 0; hd < NH; ++hd) {
    const float v = h[(size_t)c * ND + hd * DD + lane];
    float ps = v * a_src[hd * DD + lane];
    float pd = v * a_dst[hd * DD + lane];
#pragma unroll
    for (int off = 32; off > 0; off >>= 1) {
      ps += __shfl_xor(ps, off);
      pd += __shfl_xor(pd, off);
    }
    if (lane == 0) {
      asrc[hd * CN + c] = ps;
      adst[hd * CN + c] = pd;
    }
  }
}

// ---------------- Kernel C: fused masked softmax + attn@h per head
// Grid: (CN/32 i-tiles, NH heads). Block = 256 threads.
// Each block: 32 rows i, one head, loops over all j in chunks of 64.
// Z accumulated alongside the GEMM (extra "ones" column), divide at epilogue.
__global__ __launch_bounds__(256) void k_attn(const float* __restrict__ h,
                                              const int* __restrict__ adj,
                                              const float* __restrict__ asrc,
                                              const float* __restrict__ adst,
                                              float* __restrict__ out) {
  __shared__ float h_lds[64][68];  // [jj][d], padded
  __shared__ float w_lds[64][34];  // [jj][i], padded (float2-aligned reads)
  __shared__ float s_lds[32];
  __shared__ float z_lds[32];
  const int t = threadIdx.x;
  const int tx = t & 15, ty = t >> 4;  // tx -> d-group (4 d), ty -> i-pair (2 i)
  const int head = blockIdx.y;
  const int i0 = blockIdx.x * 32;
  if (t < 32) s_lds[t] = asrc[head * CN + i0 + t];
  float4 acc0 = make_float4(0.f, 0.f, 0.f, 0.f);
  float4 acc1 = make_float4(0.f, 0.f, 0.f, 0.f);
  float z0 = 0.f, z1 = 0.f;
  const float* __restrict__ adh = adst + head * CN;

  for (int j0 = 0; j0 < CN; j0 += 64) {
    __syncthreads();  // protect LDS from previous iteration's readers
    // stage h chunk [64 j][64 d] for this head (coalesced 256B rows)
    {
      const int d = t & 63;
      const int jb = t >> 6;
#pragma unroll
      for (int p = 0; p < 16; ++p) {
        const int jj = p * 4 + jb;
        h_lds[jj][d] = h[(size_t)(j0 + jj) * ND + head * DD + d];
      }
    }
    // build w chunk: w[j][i] = adj(i,j) ? exp(leaky(s_i + d_j)) : 0
    {
      const int j = t & 63;  // j fastest -> coalesced adj reads
      const int ib = t >> 6;
      const float dj = adh[j0 + j];
#pragma unroll
      for (int p = 0; p < 8; ++p) {
        const int i = p * 4 + ib;
        const int a = adj[(size_t)(i0 + i) * CN + j0 + j];
        float e = s_lds[i] + dj;
        e = (e >= 0.f) ? e : NEG * e;
        w_lds[j][i] = a ? __expf(e) : 0.f;
      }
    }
    __syncthreads();
    // rank-1-update micro-GEMM: 2 i x 4 d per thread
#pragma unroll 8
    for (int jj = 0; jj < 64; ++jj) {
      const float2 wv = *(const float2*)&w_lds[jj][ty * 2];
      const float4 hv = *(const float4*)&h_lds[jj][tx * 4];
      acc0.x += wv.x * hv.x; acc0.y += wv.x * hv.y;
      acc0.z += wv.x * hv.z; acc0.w += wv.x * hv.w;
      acc1.x += wv.y * hv.x; acc1.y += wv.y * hv.y;
      acc1.z += wv.y * hv.z; acc1.w += wv.y * hv.w;
      if (tx == 0) { z0 += wv.x; z1 += wv.y; }
    }
  }
  if (tx == 0) { z_lds[ty * 2] = z0; z_lds[ty * 2 + 1] = z1; }
  __syncthreads();
  const float iz0 = 1.f / z_lds[ty * 2];
  const float iz1 = 1.f / z_lds[ty * 2 + 1];
  float4 o0 = make_float4(acc0.x * iz0, acc0.y * iz0, acc0.z * iz0, acc0.w * iz0);
  float4 o1 = make_float4(acc1.x * iz1, acc1.y * iz1, acc1.z * iz1, acc1.w * iz1);
  *(float4*)&out[(size_t)(i0 + ty * 2) * ND + head * DD + tx * 4] = o0;
  *(float4*)&out[(size_t)(i0 + ty * 2 + 1) * ND + head * DD + tx * 4] = o1;
}

extern "C" void kernel_launch(void* const* d_in, const int* in_sizes, int n_in,
                              void* d_out, int out_size, void* d_ws, size_t ws_size,
                              hipStream_t stream) {
  const float* x = (const float*)d_in[0];
  const int* adj = (const int*)d_in[1];
  const float* W = (const float*)d_in[2];
  const float* a_src = (const float*)d_in[3];
  const float* a_dst = (const float*)d_in[4];
  float* out = (float*)d_out;

  float* h = (float*)d_ws;                    // 4096*256 fp32 = 4 MB
  float* asrc = h + (size_t)CN * ND;          // 4*4096
  float* adst = asrc + (size_t)NH * CN;       // 4*4096

  k_gemm_h<<<dim3(ND / 64, CN / 64), 256, 0, stream>>>(x, W, h);
  k_alpha<<<dim3(CN / 4), 256, 0, stream>>>(h, a_src, a_dst, asrc, adst);
  k_attn<<<dim3(CN / 32, NH), 256, 0, stream>>>(h, adj, asrc, adst, out);
}

// Round 2
// 214.767 us; speedup vs baseline: 3.1401x; 3.1401x over previous
//
#include <hip/hip_runtime.h>
#include <math.h>

#define CN 4096
#define KDIM 256
#define ND 256   // H * D
#define NH 4
#define DD 64
#define NEG 0.2f
#define L2E 1.44269504f

typedef __attribute__((ext_vector_type(8))) short short8;   // 8 bf16 (4 VGPRs)
typedef __attribute__((ext_vector_type(4))) float floatx4;  // MFMA acc

union S8I4 { int i[4]; short8 s; };

// pack two fp32 -> one dword of 2 bf16 (truncation), via v_perm_b32
__device__ inline int pack2_trunc(float a, float b) {
  return (int)__builtin_amdgcn_perm(__float_as_uint(b), __float_as_uint(a), 0x07060302u);
}
// RNE version (used for h^T, computed once)
__device__ inline int pack2_rne(float a, float b) {
  unsigned ua = __float_as_uint(a), ub = __float_as_uint(b);
  ua += 0x7fffu + ((ua >> 16) & 1u);
  ub += 0x7fffu + ((ub >> 16) & 1u);
  return (int)__builtin_amdgcn_perm(ub, ua, 0x07060302u);
}

__device__ inline float bf2f(unsigned short u) {
  return __uint_as_float(((unsigned)u) << 16);
}

// score -> exp2 domain: x already scaled by log2(e)
__device__ inline float wval(float spre, float dpre, int a) {
  float x = spre + dpre;
  x = fmaxf(x, NEG * x);       // LeakyReLU (valid in log2e-scaled domain)
  x = a ? x : -1e38f;          // mask -> exp2 -> 0
  return __builtin_amdgcn_exp2f(x);
}

// ---------------- Kernel A: h = x @ W, emitted as hT bf16 [NH][DD][CN]
__global__ __launch_bounds__(256) void k_gemm_h(const float* __restrict__ x,
                                                const float* __restrict__ W,
                                                unsigned short* __restrict__ hT) {
  __shared__ float As[16][68];  // [k][i]
  __shared__ float Bs[16][68];  // [k][c]
  const int t = threadIdx.x;
  const int tx = t & 15, ty = t >> 4;
  const int i0 = blockIdx.y * 64, c0 = blockIdx.x * 64;  // c0 = head*64
  float acc[4][4] = {};
  for (int k0 = 0; k0 < KDIM; k0 += 16) {
    __syncthreads();
    {
      const int kc = t & 15;
      const int ib = t >> 4;
#pragma unroll
      for (int p = 0; p < 4; ++p) {
        const int i = p * 16 + ib;
        As[kc][i] = x[(size_t)(i0 + i) * KDIM + k0 + kc];
      }
      const int c = t & 63;
      const int kb = t >> 6;
#pragma unroll
      for (int p = 0; p < 4; ++p) {
        const int k = p * 4 + kb;
        Bs[k][c] = W[(size_t)(k0 + k) * ND + c0 + c];
      }
    }
    __syncthreads();
#pragma unroll
    for (int kk = 0; kk < 16; ++kk) {
      const float4 a4 = *(const float4*)&As[kk][ty * 4];
      const float4 b4 = *(const float4*)&Bs[kk][tx * 4];
      const float a[4] = {a4.x, a4.y, a4.z, a4.w};
      const float b[4] = {b4.x, b4.y, b4.z, b4.w};
#pragma unroll
      for (int ii = 0; ii < 4; ++ii)
#pragma unroll
        for (int cc = 0; cc < 4; ++cc) acc[ii][cc] += a[ii] * b[cc];
    }
  }
  // epilogue: hT[head][c - head*64][i] = bf16(acc), RNE
  unsigned short* hTb = hT + (size_t)blockIdx.x * DD * CN;  // blockIdx.x == head
#pragma unroll
  for (int cc = 0; cc < 4; ++cc) {
    uint2 v;
    v.x = (unsigned)pack2_rne(acc[0][cc], acc[1][cc]);
    v.y = (unsigned)pack2_rne(acc[2][cc], acc[3][cc]);
    *(uint2*)(hTb + (size_t)(tx * 4 + cc) * CN + i0 + ty * 4) = v;
  }
}

// ---------------- Kernel B: alpha_src[h][c], alpha_dst[h][c] from hT bf16
__global__ __launch_bounds__(256) void k_alpha(const unsigned short* __restrict__ hT,
                                               const float* __restrict__ a_src,
                                               const float* __restrict__ a_dst,
                                               float* __restrict__ asrc,
                                               float* __restrict__ adst) {
  const int c = blockIdx.x * 256 + threadIdx.x;
  const int hd = blockIdx.y;
  const unsigned short* hb = hT + (size_t)hd * DD * CN;
  float ss = 0.f, sd = 0.f;
#pragma unroll 8
  for (int d = 0; d < DD; ++d) {
    const float v = bf2f(hb[(size_t)d * CN + c]);
    ss += v * a_src[hd * DD + d];
    sd += v * a_dst[hd * DD + d];
  }
  asrc[hd * CN + c] = ss;
  adst[hd * CN + c] = sd;
}

// ---------------- Kernel C: fused masked softmax + attn@h, MFMA bf16
// Grid: (CN/64 i-tiles, NH heads), block = 256 (4 waves).
// Wave ww owns rows [i0+16ww, i0+16ww+16), all 64 d. No LDS, no barriers.
__global__ __launch_bounds__(256) void k_attn(const unsigned short* __restrict__ hT,
                                              const int* __restrict__ adj,
                                              const float* __restrict__ asrc,
                                              const float* __restrict__ adst,
                                              float* __restrict__ out) {
  const int t = threadIdx.x;
  const int lane = t & 63, ww = t >> 6;
  const int n = lane & 15, q = lane >> 4;
  const int head = blockIdx.y;
  const int i0 = blockIdx.x * 64;
  const int i = i0 + ww * 16 + n;  // this lane's A-row (m = lane&15)
  const float spre = asrc[head * CN + i] * L2E;
  const float* __restrict__ adh = adst + head * CN;
  const unsigned short* __restrict__ hTb = hT + (size_t)head * DD * CN;
  const int* __restrict__ adjr = adj + (size_t)i * CN;

  floatx4 acc[4] = {};
  float z = 0.f;

  for (int j0 = 0; j0 < CN; j0 += 64) {
    // ---- B fragments: hT rows, k = q*8+elem  (L2-resident, 16B/lane each)
    short8 B[4][2];
#pragma unroll
    for (int tt = 0; tt < 4; ++tt) {
      const unsigned short* bp = hTb + (size_t)(tt * 16 + n) * CN + j0 + q * 8;
      B[tt][0] = *(const short8*)(bp);
      B[tt][1] = *(const short8*)(bp + 32);
    }
    // ---- adj + alpha_dst for this lane's 16 k-slots
    int av[16];
    {
      const int4 b0 = *(const int4*)(adjr + j0 + q * 8);
      const int4 b1 = *(const int4*)(adjr + j0 + q * 8 + 4);
      const int4 b2 = *(const int4*)(adjr + j0 + 32 + q * 8);
      const int4 b3 = *(const int4*)(adjr + j0 + 32 + q * 8 + 4);
      av[0]=b0.x; av[1]=b0.y; av[2]=b0.z; av[3]=b0.w;
      av[4]=b1.x; av[5]=b1.y; av[6]=b1.z; av[7]=b1.w;
      av[8]=b2.x; av[9]=b2.y; av[10]=b2.z; av[11]=b2.w;
      av[12]=b3.x; av[13]=b3.y; av[14]=b3.z; av[15]=b3.w;
    }
    float dv[16];
    {
      const float4 t0 = *(const float4*)(adh + j0 + q * 8);
      const float4 t1 = *(const float4*)(adh + j0 + q * 8 + 4);
      const float4 t2 = *(const float4*)(adh + j0 + 32 + q * 8);
      const float4 t3 = *(const float4*)(adh + j0 + 32 + q * 8 + 4);
      dv[0]=t0.x; dv[1]=t0.y; dv[2]=t0.z; dv[3]=t0.w;
      dv[4]=t1.x; dv[5]=t1.y; dv[6]=t1.z; dv[7]=t1.w;
      dv[8]=t2.x; dv[9]=t2.y; dv[10]=t2.z; dv[11]=t2.w;
      dv[12]=t3.x; dv[13]=t3.y; dv[14]=t3.z; dv[15]=t3.w;
    }
    // ---- w = exp(leaky(s_i + d_j)) masked; accumulate Z; pack to bf16 A-frags
    float f[16];
#pragma unroll
    for (int u = 0; u < 16; ++u) {
      f[u] = wval(spre, dv[u] * L2E, av[u]);
      z += f[u];
    }
    S8I4 A0, A1;
#pragma unroll
    for (int u = 0; u < 4; ++u) {
      A0.i[u] = pack2_trunc(f[2 * u], f[2 * u + 1]);
      A1.i[u] = pack2_trunc(f[8 + 2 * u], f[8 + 2 * u + 1]);
    }
    // ---- 8 MFMAs: out_tile[16i x 64d] += w[16i x 64j] * hT[64j x 64d]
#pragma unroll
    for (int tt = 0; tt < 4; ++tt) {
      acc[tt] = __builtin_amdgcn_mfma_f32_16x16x32_bf16(A0.s, B[tt][0], acc[tt], 0, 0, 0);
      acc[tt] = __builtin_amdgcn_mfma_f32_16x16x32_bf16(A1.s, B[tt][1], acc[tt], 0, 0, 0);
    }
  }

  // ---- softmax denominator: reduce across quads (lanes i, i+16, i+32, i+48)
  z += __shfl_xor(z, 16);
  z += __shfl_xor(z, 32);

  // ---- epilogue: C/D layout row m = q*4+r, col = lane&15
  const int irow0 = i0 + ww * 16;
#pragma unroll
  for (int r = 0; r < 4; ++r) {
    const float zz = __shfl(z, q * 4 + r);  // lane (q*4+r) holds Z for row q*4+r
    const float iz = 1.0f / zz;
    const size_t row = (size_t)(irow0 + q * 4 + r) * ND + head * DD + n;
#pragma unroll
    for (int tt = 0; tt < 4; ++tt) out[row + tt * 16] = acc[tt][r] * iz;
  }
}

extern "C" void kernel_launch(void* const* d_in, const int* in_sizes, int n_in,
                              void* d_out, int out_size, void* d_ws, size_t ws_size,
                              hipStream_t stream) {
  const float* x = (const float*)d_in[0];
  const int* adj = (const int*)d_in[1];
  const float* W = (const float*)d_in[2];
  const float* a_src = (const float*)d_in[3];
  const float* a_dst = (const float*)d_in[4];
  float* out = (float*)d_out;

  unsigned short* hT = (unsigned short*)d_ws;          // [NH][DD][CN] bf16 = 2 MB
  float* asrc = (float*)(hT + (size_t)NH * DD * CN);   // [NH][CN]
  float* adst = asrc + (size_t)NH * CN;                // [NH][CN]

  k_gemm_h<<<dim3(ND / 64, CN / 64), 256, 0, stream>>>(x, W, hT);
  k_alpha<<<dim3(CN / 256, NH), 256, 0, stream>>>(hT, a_src, a_dst, asrc, adst);
  k_attn<<<dim3(CN / 64, NH), 256, 0, stream>>>(hT, adj, asrc, adst, out);
}

// Round 3
// 201.444 us; speedup vs baseline: 3.3478x; 1.0661x over previous
//
#include <hip/hip_runtime.h>
#include <math.h>

#define CN 4096
#define KDIM 256
#define ND 256   // H * D
#define NH 4
#define DD 64
#define NEG 0.2f
#define L2E 1.44269504f

typedef __attribute__((ext_vector_type(8))) short short8;   // 8 bf16 (4 VGPRs)
typedef __attribute__((ext_vector_type(4))) float floatx4;  // MFMA acc

union S8I4 { int i[4]; short8 s; };

// pack two fp32 -> one dword of 2 bf16 (truncation), via v_perm_b32
__device__ inline int pack2_trunc(float a, float b) {
  return (int)__builtin_amdgcn_perm(__float_as_uint(b), __float_as_uint(a), 0x07060302u);
}
// RNE version (used for h^T, computed once)
__device__ inline int pack2_rne(float a, float b) {
  unsigned ua = __float_as_uint(a), ub = __float_as_uint(b);
  ua += 0x7fffu + ((ua >> 16) & 1u);
  ub += 0x7fffu + ((ub >> 16) & 1u);
  return (int)__builtin_amdgcn_perm(ub, ua, 0x07060302u);
}

// score (already in log2e domain) -> exp2, with adjacency mask
__device__ inline float wval(float x, int a) {
  x = fmaxf(x, NEG * x);       // LeakyReLU (positive scale commutes)
  x = a ? x : -1e38f;          // mask -> exp2 -> 0
  return __builtin_amdgcn_exp2f(x);
}

// ---------------- Kernel A: h = x @ W -> hT bf16 [NH][DD][CN], fused alpha
// Tile 32(i) x 64(c=one head), 256 threads, 2x4 per thread. Grid (NH, CN/32).
__global__ __launch_bounds__(256) void k_gemm_h(const float* __restrict__ x,
                                                const float* __restrict__ W,
                                                const float* __restrict__ a_src,
                                                const float* __restrict__ a_dst,
                                                unsigned short* __restrict__ hT,
                                                float* __restrict__ asrc,
                                                float* __restrict__ adst) {
  __shared__ float As[16][36];  // [k][i]
  __shared__ float Bs[16][68];  // [k][c]
  const int t = threadIdx.x;
  const int tx = t & 15, ty = t >> 4;   // tx -> 4 cols, ty -> 2 rows
  const int head = blockIdx.x;
  const int c0 = head * 64;
  const int i0 = blockIdx.y * 32;
  float acc[2][4] = {};
  for (int k0 = 0; k0 < KDIM; k0 += 16) {
    __syncthreads();
    {
      const int k = t & 15, ib = t >> 4;
      As[k][ib] = x[(size_t)(i0 + ib) * KDIM + k0 + k];
      As[k][ib + 16] = x[(size_t)(i0 + ib + 16) * KDIM + k0 + k];
    }
    {
      const int c = t & 63, kb = t >> 6;
#pragma unroll
      for (int p = 0; p < 4; ++p)
        Bs[kb + 4 * p][c] = W[(size_t)(k0 + kb + 4 * p) * ND + c0 + c];
    }
    __syncthreads();
#pragma unroll
    for (int kk = 0; kk < 16; ++kk) {
      const float2 a2 = *(const float2*)&As[kk][ty * 2];
      const float4 b4 = *(const float4*)&Bs[kk][tx * 4];
      acc[0][0] += a2.x * b4.x; acc[0][1] += a2.x * b4.y;
      acc[0][2] += a2.x * b4.z; acc[0][3] += a2.x * b4.w;
      acc[1][0] += a2.y * b4.x; acc[1][1] += a2.y * b4.y;
      acc[1][2] += a2.y * b4.z; acc[1][3] += a2.y * b4.w;
    }
  }
  // hT[head][d = tx*4+cc][i0 + ty*2 + {0,1}] = bf16(acc)
  unsigned short* hTb = hT + (size_t)head * DD * CN;
#pragma unroll
  for (int cc = 0; cc < 4; ++cc)
    *(unsigned*)(hTb + (size_t)(tx * 4 + cc) * CN + i0 + ty * 2) =
        (unsigned)pack2_rne(acc[0][cc], acc[1][cc]);
  // fused alpha: asrc/adst[head][i] = (h_row . a) * L2E   (fp32 accumulators)
  const float4 as4 = *(const float4*)&a_src[head * DD + tx * 4];
  const float4 ad4 = *(const float4*)&a_dst[head * DD + tx * 4];
  float ps0 = acc[0][0]*as4.x + acc[0][1]*as4.y + acc[0][2]*as4.z + acc[0][3]*as4.w;
  float ps1 = acc[1][0]*as4.x + acc[1][1]*as4.y + acc[1][2]*as4.z + acc[1][3]*as4.w;
  float pd0 = acc[0][0]*ad4.x + acc[0][1]*ad4.y + acc[0][2]*ad4.z + acc[0][3]*ad4.w;
  float pd1 = acc[1][0]*ad4.x + acc[1][1]*ad4.y + acc[1][2]*ad4.z + acc[1][3]*ad4.w;
#pragma unroll
  for (int off = 1; off < 16; off <<= 1) {
    ps0 += __shfl_xor(ps0, off); ps1 += __shfl_xor(ps1, off);
    pd0 += __shfl_xor(pd0, off); pd1 += __shfl_xor(pd1, off);
  }
  if (tx == 0) {
    const int i = i0 + ty * 2;
    asrc[head * CN + i]     = ps0 * L2E;
    asrc[head * CN + i + 1] = ps1 * L2E;
    adst[head * CN + i]     = pd0 * L2E;
    adst[head * CN + i + 1] = pd1 * L2E;
  }
}

// ---------------- Kernel B: fused masked softmax + attn@h, MFMA bf16
// Grid (CN/32, NH), block 512 = 8 waves: wave w -> rg = w&1 (16-row group),
// js = w>>1 (quarter of the j range). Partials combined through LDS.
__global__ __launch_bounds__(512, 4) void k_attn(const unsigned short* __restrict__ hT,
                                                 const int* __restrict__ adj,
                                                 const float* __restrict__ asrc,
                                                 const float* __restrict__ adst,
                                                 float* __restrict__ out) {
  __shared__ float red[2][3][20][64];  // [rg][js-1][frag][lane], 30 KB
  const int t = threadIdx.x;
  const int lane = t & 63, w = t >> 6;
  const int rg = w & 1, js = w >> 1;
  const int n = lane & 15, q = lane >> 4;
  const int head = blockIdx.y;
  const int i0 = blockIdx.x * 32;
  const int i = i0 + rg * 16 + n;  // this lane's A-row
  const float spre = asrc[head * CN + i];               // pre-scaled by log2(e)
  const float* __restrict__ adh = adst + head * CN;     // pre-scaled by log2(e)
  const unsigned short* __restrict__ hTb = hT + (size_t)head * DD * CN;
  const int* __restrict__ adjr = adj + (size_t)i * CN;

  short8 ONES;
#pragma unroll
  for (int u = 0; u < 8; ++u) ONES[u] = (short)0x3F80;  // bf16 1.0

  floatx4 acc[4] = {};
  floatx4 accz = {};

  for (int c = 0; c < 16; ++c) {
    const int j0 = js * 1024 + c * 64;
    // B fragments: hT rows (d = tt*16+n), k = q*8+e  (L2-resident)
    short8 B[4][2];
#pragma unroll
    for (int tt = 0; tt < 4; ++tt) {
      const unsigned short* bp = hTb + (size_t)(tt * 16 + n) * CN + j0 + q * 8;
      B[tt][0] = *(const short8*)(bp);
      B[tt][1] = *(const short8*)(bp + 32);
    }
    // scores -> bf16 A fragments, 4 j's at a time (low register pressure)
    S8I4 A0, A1;
#pragma unroll
    for (int g = 0; g < 4; ++g) {
      const int base = j0 + (g >> 1) * 32 + q * 8 + (g & 1) * 4;
      const int4 av = *(const int4*)(adjr + base);
      const float4 dv = *(const float4*)(adh + base);
      const float f0 = wval(spre + dv.x, av.x);
      const float f1 = wval(spre + dv.y, av.y);
      const float f2 = wval(spre + dv.z, av.z);
      const float f3 = wval(spre + dv.w, av.w);
      int* Ai = (g < 2) ? A0.i : A1.i;
      Ai[(g & 1) * 2]     = pack2_trunc(f0, f1);
      Ai[(g & 1) * 2 + 1] = pack2_trunc(f2, f3);
    }
    // numerator: out_tile[16i x 64d] += w * hT ; Z: row sums via ones-B
#pragma unroll
    for (int tt = 0; tt < 4; ++tt) {
      acc[tt] = __builtin_amdgcn_mfma_f32_16x16x32_bf16(A0.s, B[tt][0], acc[tt], 0, 0, 0);
      acc[tt] = __builtin_amdgcn_mfma_f32_16x16x32_bf16(A1.s, B[tt][1], acc[tt], 0, 0, 0);
    }
    accz = __builtin_amdgcn_mfma_f32_16x16x32_bf16(A0.s, ONES, accz, 0, 0, 0);
    accz = __builtin_amdgcn_mfma_f32_16x16x32_bf16(A1.s, ONES, accz, 0, 0, 0);
  }

  // combine the 4 j-splits through LDS
  if (js > 0) {
#pragma unroll
    for (int tt = 0; tt < 4; ++tt)
#pragma unroll
      for (int r = 0; r < 4; ++r) red[rg][js - 1][tt * 4 + r][lane] = acc[tt][r];
#pragma unroll
    for (int r = 0; r < 4; ++r) red[rg][js - 1][16 + r][lane] = accz[r];
  }
  __syncthreads();
  if (js == 0) {
#pragma unroll
    for (int s = 0; s < 3; ++s) {
#pragma unroll
      for (int tt = 0; tt < 4; ++tt)
#pragma unroll
        for (int r = 0; r < 4; ++r) acc[tt][r] += red[rg][s][tt * 4 + r][lane];
#pragma unroll
      for (int r = 0; r < 4; ++r) accz[r] += red[rg][s][16 + r][lane];
    }
    // epilogue: C/D row = q*4+r (accz[r] = that row's Z, replicated over n)
#pragma unroll
    for (int r = 0; r < 4; ++r) {
      const float iz = 1.0f / accz[r];
      const size_t row = (size_t)(i0 + rg * 16 + q * 4 + r) * ND + head * DD + n;
#pragma unroll
      for (int tt = 0; tt < 4; ++tt) out[row + tt * 16] = acc[tt][r] * iz;
    }
  }
}

extern "C" void kernel_launch(void* const* d_in, const int* in_sizes, int n_in,
                              void* d_out, int out_size, void* d_ws, size_t ws_size,
                              hipStream_t stream) {
  const float* x = (const float*)d_in[0];
  const int* adj = (const int*)d_in[1];
  const float* W = (const float*)d_in[2];
  const float* a_src = (const float*)d_in[3];
  const float* a_dst = (const float*)d_in[4];
  float* out = (float*)d_out;

  unsigned short* hT = (unsigned short*)d_ws;          // [NH][DD][CN] bf16 = 2 MB
  float* asrc = (float*)(hT + (size_t)NH * DD * CN);   // [NH][CN]
  float* adst = asrc + (size_t)NH * CN;                // [NH][CN]

  k_gemm_h<<<dim3(NH, CN / 32), 256, 0, stream>>>(x, W, a_src, a_dst, hT, asrc, adst);
  k_attn<<<dim3(CN / 32, NH), 512, 0, stream>>>(hT, adj, asrc, adst, out);
}